// Round 11
// baseline (5347.392 us; speedup 1.0000x reference)
//
#include <hip/hip_runtime.h>
#include <stddef.h>

typedef unsigned int u32;

#define TT 512
#define TC 64        // timestep chunk
#define NCHUNK 8

__device__ __forceinline__ float sigmoidf_(float x) {
    return 1.0f / (1.0f + __expf(-x));
}
__device__ __forceinline__ float tanhf_(float x) {
    float ax = fabsf(x);
    float e = __expf(-2.0f * ax);
    float t = (1.0f - e) / (1.0f + e);
    return copysignf(t, x);
}

// ---- per-access coherent (IF$-level) ops: no cache-wide inv/wb, no RMW ----
__device__ __forceinline__ float4 ldg_cv4(const float* p) {
    float4 v;
    asm volatile("global_load_dwordx4 %0, %1, off sc0 sc1\n\t"
                 "s_waitcnt vmcnt(0)"
                 : "=v"(v) : "v"(p) : "memory");
    return v;
}
__device__ __forceinline__ u32 ldg_cu32(const u32* p) {
    u32 v;
    asm volatile("global_load_dword %0, %1, off sc0 sc1\n\t"
                 "s_waitcnt vmcnt(0)"
                 : "=v"(v) : "v"(p) : "memory");
    return v;
}
__device__ __forceinline__ void stg_cv1(float* p, float v) {
    asm volatile("global_store_dword %0, %1, off sc0 sc1"
                 :: "v"(p), "v"(v) : "memory");
}
__device__ __forceinline__ void stg_cu32(u32* p, u32 v) {
    asm volatile("global_store_dword %0, %1, off sc0 sc1"
                 :: "v"(p), "v"(v) : "memory");
}

// ============================================================================
// proj2: paired input-projection GEMMs (z=0: set A, z=1: set B).
//   xW[tl][j][b] = sum_k W[j][k] * X[b*sXb + (tb + tl)*sXt + k] + bih[j] + bhh[j]
//   tb < 0 -> half inactive.
// ============================================================================
#define APITCH 132
#define BPITCH 132

__global__ void __launch_bounds__(256, 2)
proj2(const float* __restrict__ WA, const float* __restrict__ bihA,
      const float* __restrict__ bhhA, const float* __restrict__ XA,
      size_t sXbA, size_t sXtA, int tbA, float* __restrict__ xWA,
      const float* __restrict__ WB, const float* __restrict__ bihB,
      const float* __restrict__ bhhB, const float* __restrict__ XB,
      size_t sXbB, size_t sXtB, int tbB, float* __restrict__ xWB)
{
    const int half = blockIdx.z;
    const int tb = half ? tbB : tbA;
    if (tb < 0) return;
    const float* W   = half ? WB   : WA;
    const float* bih = half ? bihB : bihA;
    const float* bhh = half ? bhhB : bhhA;
    const float* X   = half ? XB   : XA;
    const size_t sXb = half ? sXbB : sXbA;
    const size_t sXt = half ? sXtB : sXtA;
    float* xW        = half ? xWB  : xWA;

    __shared__ float As[32][APITCH];   // [k][m]
    __shared__ float Bs[32][BPITCH];   // [k][n]
    const int tid = threadIdx.x;
    const int mbase = blockIdx.x * 128;
    const int nt = blockIdx.y;
    const int tm = tid >> 4;
    const int tn = tid & 15;
    float acc[8][8] = {};

    for (int kc = 0; kc < 512; kc += 32) {
        __syncthreads();
#pragma unroll
        for (int u = 0; u < 4; ++u) {
            const int f = u * 256 + tid;
            const int m = f >> 3, k4 = f & 7;
            const float4 v = *(const float4*)(W + (size_t)(mbase + m) * 512 + kc + k4 * 4);
            As[k4 * 4 + 0][m] = v.x; As[k4 * 4 + 1][m] = v.y;
            As[k4 * 4 + 2][m] = v.z; As[k4 * 4 + 3][m] = v.w;
        }
#pragma unroll
        for (int u = 0; u < 4; ++u) {
            const int f = u * 256 + tid;
            const int n = f >> 3, k4 = f & 7;
            const int tl = n >> 5, b = n & 31;
            const float4 v = *(const float4*)(X + (size_t)b * sXb +
                                              (size_t)(tb + nt * 4 + tl) * sXt + kc + k4 * 4);
            Bs[k4 * 4 + 0][n] = v.x; Bs[k4 * 4 + 1][n] = v.y;
            Bs[k4 * 4 + 2][n] = v.z; Bs[k4 * 4 + 3][n] = v.w;
        }
        __syncthreads();
#pragma unroll 8
        for (int kk = 0; kk < 32; ++kk) {
            const float4 a0 = *(const float4*)&As[kk][tm * 8];
            const float4 a1 = *(const float4*)&As[kk][tm * 8 + 4];
            const float4 b0 = *(const float4*)&Bs[kk][tn * 8];
            const float4 b1 = *(const float4*)&Bs[kk][tn * 8 + 4];
            const float am[8] = {a0.x,a0.y,a0.z,a0.w,a1.x,a1.y,a1.z,a1.w};
            const float bn[8] = {b0.x,b0.y,b0.z,b0.w,b1.x,b1.y,b1.z,b1.w};
#pragma unroll
            for (int i = 0; i < 8; ++i)
#pragma unroll
                for (int j = 0; j < 8; ++j)
                    acc[i][j] = fmaf(am[i], bn[j], acc[i][j]);
        }
    }
    const int tl_loc = nt * 4 + (tn >> 2);
    const int bcol = (tn & 3) * 8;
#pragma unroll
    for (int i = 0; i < 8; ++i) {
        const int m = mbase + tm * 8 + i;
        const float bias = bih[m] + bhh[m];
        float* dst = xW + ((size_t)tl_loc * 2048 + m) * 32 + bcol;
        float4 v0 = {acc[i][0] + bias, acc[i][1] + bias, acc[i][2] + bias, acc[i][3] + bias};
        float4 v1 = {acc[i][4] + bias, acc[i][5] + bias, acc[i][6] + bias, acc[i][7] + bias};
        *(float4*)dst = v0;
        *(float4*)(dst + 4) = v1;
    }
}

// ============================================================================
// lstm_rec2: paired recurrences (bid<256: set A, bid>=256: set B), independent.
//   R10 engine (112 VGPR, butterfly reduce) with a low-bandwidth sync surface:
//   - producer: 64 x 4B h stores (sc0sc1, h-only ring) -> s_waitcnt vmcnt(0)
//     (wave-level: orders ALL update lanes' stores) -> lane0 stores prog=t+1.
//   - consumer: 32 lanes poll 32 prog words (128B/iter, was 16KB/iter),
//     __syncthreads, then ONE 16B coherent h load per thread.
//   chain = lb&7 (4 batches), rbi = lb>>3 (16 hidden -> 64 gate rows).
//   t0 < 0 -> half inactive. hbuf addressed as hbuf + (t - tsub)*sT + b*sB + h.
// ============================================================================
__global__ void __launch_bounds__(512, 1)
lstm_rec2(const float* __restrict__ WhhA, const float* __restrict__ xWA,
          float* __restrict__ hbufA, size_t sTA, size_t sBA, int tsubA,
          float* __restrict__ cstA, float* __restrict__ ringA,
          u32* __restrict__ progA, int t0A,
          const float* __restrict__ WhhB, const float* __restrict__ xWB,
          float* __restrict__ hbufB, size_t sTB, size_t sBB, int tsubB,
          float* __restrict__ cstB, float* __restrict__ ringB,
          u32* __restrict__ progB, int t0B)
{
    const int half = blockIdx.x >> 8;
    const int t0 = half ? t0B : t0A;
    if (t0 < 0) return;
    const float* Whh = half ? WhhB : WhhA;
    const float* xW  = half ? xWB  : xWA;
    float* hbuf      = half ? hbufB : hbufA;
    const size_t sT  = half ? sTB : sTA;
    const size_t sB  = half ? sBB : sBA;
    const int tsub   = half ? tsubB : tsubA;
    float* cst       = half ? cstB : cstA;
    float* ring      = half ? ringB : ringA;     // [4][32][512] h-only
    u32* prog        = half ? progB : progA;     // [8][32]

    __shared__ float xh[4][512];             // quad-swizzled h(t-1)   8 KB
    __shared__ float gl[16][4][4];           // [hl][b][gate]          1 KB

    const int tid = threadIdx.x;
    const int lb = blockIdx.x & 255;
    const int chain = lb & 7;
    const int rbi = lb >> 3;
    const int hb = rbi * 16;                 // hidden slice [hb, hb+16)
    const int bb = chain * 4;                // batch slice [bb, bb+4)

    const int rgrp = tid >> 4;               // 0..31 -> rows rgrp*2, rgrp*2+1
    const int ks = tid & 15;                 // 0..15 -> k in [ks*32, ks*32+32)
    const int ks7 = ks & 7;

    // ---- load W_hh slice into registers (once): 2 rows x 32 k = 64 VGPRs ----
    float w[2][32];
#pragma unroll
    for (int i = 0; i < 2; ++i) {
        const int r = rgrp * 2 + i;                       // gate g=r>>4, hl=r&15
        const int j = ((r >> 4) << 9) + hb + (r & 15);
#pragma unroll
        for (int q8 = 0; q8 < 8; ++q8) {
            const float4 v = *(const float4*)(Whh + (size_t)j * 512 + ks * 32 + q8 * 4);
            w[i][q8 * 4 + 0] = v.x; w[i][q8 * 4 + 1] = v.y;
            w[i][q8 * 4 + 2] = v.z; w[i][q8 * 4 + 3] = v.w;
        }
    }
    // xwv-lane decode (ks<8): lane adds xW for (row i_x = ks>>2, batch b_x = ks&3)
    const int i_x = ks >> 2, b_x = ks & 3;
    const int r_x = rgrp * 2 + i_x;
    const int j_x = ((r_x >> 4) << 9) + hb + (r_x & 15);
    // consumer staging decode: batch b_s, h-quad q (one 16B load per thread)
    const int b_s = tid >> 7, q = tid & 127;
    const float* hq_base = ring + (size_t)(bb + b_s) * 512 + (q << 2);
    // update decode (tid<64)
    const int b_u = tid >> 4, hl_u = tid & 15;
    float c_reg = 0.0f;
    if (tid < 64) c_reg = cst[(size_t)(bb + b_u) * 512 + hb + hl_u];

    u32* progc = prog + chain * 32;          // this chain's 32 progress words
    u32* prog_self = progc + rbi;

    __syncthreads();

    for (int t = t0; t < t0 + TC; ++t) {
        // prefetch precomputed input-projection (plain cached load, no dependency)
        float xwv = 0.0f;
        if (ks < 8)
            xwv = xW[((size_t)(t - t0) * 2048 + j_x) * 32 + bb + b_x];

        if (t > 0) {
            // low-bandwidth wait: 32 lanes poll 32 per-block progress words
            if (tid < 32) {
                const u32 tt = (u32)t;
                u32 v;
                do { v = ldg_cu32(progc + tid); } while (v < tt);
            }
            __syncthreads();
            // one-shot 16B coherent load of h(t-1), XOR quad-swizzle into LDS
            const float4 hq = ldg_cv4(hq_base + (size_t)((t - 1) & 3) * (32 * 512));
            const int swq = q ^ ((q >> 3) & 7);          // bijective, conflict-free
            *(float4*)&xh[b_s][swq << 2] = hq;
        }
        __syncthreads();

        float acc[2][4] = {};
        if (t > 0) {
#pragma unroll
            for (int jj = 0; jj < 8; ++jj) {
                const int sq = ((ks << 3) + (jj ^ ks7)) << 2;   // swizzled quad offset
                const float4 x0 = *(const float4*)&xh[0][sq];
                const float4 x1 = *(const float4*)&xh[1][sq];
                const float4 x2 = *(const float4*)&xh[2][sq];
                const float4 x3 = *(const float4*)&xh[3][sq];
#pragma unroll
                for (int i = 0; i < 2; ++i) {
                    acc[i][0] = fmaf(w[i][jj*4+0], x0.x, acc[i][0]);
                    acc[i][0] = fmaf(w[i][jj*4+1], x0.y, acc[i][0]);
                    acc[i][0] = fmaf(w[i][jj*4+2], x0.z, acc[i][0]);
                    acc[i][0] = fmaf(w[i][jj*4+3], x0.w, acc[i][0]);
                    acc[i][1] = fmaf(w[i][jj*4+0], x1.x, acc[i][1]);
                    acc[i][1] = fmaf(w[i][jj*4+1], x1.y, acc[i][1]);
                    acc[i][1] = fmaf(w[i][jj*4+2], x1.z, acc[i][1]);
                    acc[i][1] = fmaf(w[i][jj*4+3], x1.w, acc[i][1]);
                    acc[i][2] = fmaf(w[i][jj*4+0], x2.x, acc[i][2]);
                    acc[i][2] = fmaf(w[i][jj*4+1], x2.y, acc[i][2]);
                    acc[i][2] = fmaf(w[i][jj*4+2], x2.z, acc[i][2]);
                    acc[i][2] = fmaf(w[i][jj*4+3], x2.w, acc[i][2]);
                    acc[i][3] = fmaf(w[i][jj*4+0], x3.x, acc[i][3]);
                    acc[i][3] = fmaf(w[i][jj*4+1], x3.y, acc[i][3]);
                    acc[i][3] = fmaf(w[i][jj*4+2], x3.z, acc[i][3]);
                    acc[i][3] = fmaf(w[i][jj*4+3], x3.w, acc[i][3]);
                }
            }
        }
        // fold xW in (each of the 8 outputs added by exactly one of lanes ks<8)
        if (ks < 8) acc[i_x][b_x] += xwv;
        // butterfly reduce over the 16 k-slice lanes (4 stages x 8 accs)
#pragma unroll
        for (int m = 1; m < 16; m <<= 1) {
#pragma unroll
            for (int i = 0; i < 2; ++i) {
#pragma unroll
                for (int b = 0; b < 4; ++b)
                    acc[i][b] += __shfl_xor(acc[i][b], m);
            }
        }
        if (ks == 0) {
#pragma unroll
            for (int i = 0; i < 2; ++i) {
                const int r = rgrp * 2 + i;
#pragma unroll
                for (int b = 0; b < 4; ++b)
                    gl[r & 15][b][r >> 4] = acc[i][b];
            }
        }
        __syncthreads();
        if (tid < 64) {  // one thread per (batch, hidden) pair
            const float4 gv = *(const float4*)&gl[hl_u][b_u][0];
            const float i_ = sigmoidf_(gv.x);
            const float f_ = sigmoidf_(gv.y);
            const float g_ = tanhf_(gv.z);
            const float o_ = sigmoidf_(gv.w);
            c_reg = f_ * c_reg + i_ * g_;
            const float hv = o_ * tanhf_(c_reg);
            // plain store for cross-dispatch consumers (GEMM / final output)
            hbuf[(size_t)(t - tsub) * sT + (size_t)(bb + b_u) * sB + hb + hl_u] = hv;
            // coherent h publish into the depth-4 ring
            stg_cv1(ring + (size_t)(t & 3) * (32 * 512) +
                    (size_t)(bb + b_u) * 512 + hb + hl_u, hv);
            asm volatile("s_waitcnt vmcnt(0)" ::: "memory");  // all 64 lanes' stores acked
            if (tid == 0) stg_cu32(prog_self, (u32)(t + 1));
        }
        __syncthreads();
    }
    if (tid < 64) cst[(size_t)(bb + b_u) * 512 + hb + hl_u] = c_reg;
}

// ============================================================================
extern "C" void kernel_launch(void* const* d_in, const int* in_sizes, int n_in,
                              void* d_out, int out_size, void* d_ws, size_t ws_size,
                              hipStream_t stream) {
    const float* inp  = (const float*)d_in[0];
    const float* Wih0 = (const float*)d_in[1];
    const float* Whh0 = (const float*)d_in[2];
    const float* bih0 = (const float*)d_in[3];
    const float* bhh0 = (const float*)d_in[4];
    const float* Wih1 = (const float*)d_in[5];
    const float* Whh1 = (const float*)d_in[6];
    const float* bih1 = (const float*)d_in[7];
    const float* bhh1 = (const float*)d_in[8];
    float* out = (float*)d_out;

    char* ws = (char*)d_ws;
    const size_t CHf = (size_t)TC * 32 * 512;               // floats per h0 chunk slot
    float* h0ring = (float*)ws;                             // 2 x [64][32][512]  8 MB
    float* xW0    = (float*)(ws + 8388608);                 // [64][2048][32]    16 MB
    float* xW1    = (float*)(ws + 25165824);                // [64][2048][32]    16 MB
    float* cst0   = (float*)(ws + 41943040);                // [32][512] x2    128 KB
    float* cst1   = cst0 + 32 * 512;
    float* ringH0 = (float*)(ws + 42074112);                // [4][32][512]    256 KB
    float* ringH1 = (float*)(ws + 42336256);                // [4][32][512]    256 KB
    u32*   prog0  = (u32*)  (ws + 42598400);                // [8][32]           1 KB
    u32*   prog1  = (u32*)  (ws + 42599424);                // [8][32]           1 KB
    // zero c-state + progress words each launch (replay-safe); ring gated by prog
    (void)hipMemsetAsync(ws + 41943040, 0, 131072 + 2 * 262144 + 2048, stream);

    const dim3 gg(16, 16, 2), gb(256);
    const dim3 rg(512), rb(512);
    const size_t sb_in = (size_t)512 * 512;                 // inp batch stride
    const size_t sT_h0 = (size_t)32 * 512;                  // h0 slot t stride

    // beat -1: g0(0) alone
    hipLaunchKernelGGL(proj2, gg, gb, 0, stream,
                       Wih0, bih0, bhh0, inp, sb_in, (size_t)512, 0, xW0,
                       Wih1, bih1, bhh1, inp, sb_in, (size_t)512, -1, xW1);
    // beat 0: r0(0) alone
    hipLaunchKernelGGL(lstm_rec2, rg, rb, 0, stream,
                       Whh0, xW0, h0ring, sT_h0, (size_t)512, 0, cst0, ringH0, prog0, 0,
                       Whh1, xW1, out, (size_t)512, sb_in, 0, cst1, ringH1, prog1, -1);

    for (int c = 0; c < NCHUNK; ++c) {
        const int t0A = (c + 1) * TC;
        const bool hasA = (c < NCHUNK - 1);
        const int t0B = c * TC;
        float* h0cur = h0ring + (size_t)(c & 1) * CHf;         // slot chunk c
        float* h0nxt = h0ring + (size_t)((c + 1) & 1) * CHf;   // slot chunk c+1
        // proj: A = g0(c+1) (x from inp, absolute t), B = g1(c) (x from h0 slot c)
        hipLaunchKernelGGL(proj2, gg, gb, 0, stream,
                           Wih0, bih0, bhh0, inp, sb_in, (size_t)512,
                           hasA ? t0A : -1, xW0,
                           Wih1, bih1, bhh1, h0cur, (size_t)512, sT_h0, 0, xW1);
        // rec: A = r0(c+1) -> h0 slot c+1 (t-local), B = r1(c) -> out (absolute t)
        hipLaunchKernelGGL(lstm_rec2, rg, rb, 0, stream,
                           Whh0, xW0, h0nxt, sT_h0, (size_t)512, t0A,
                           cst0, ringH0, prog0, hasA ? t0A : -1,
                           Whh1, xW1, out, (size_t)512, sb_in, 0,
                           cst1, ringH1, prog1, t0B);
    }
}